// Round 1
// baseline (108.535 us; speedup 1.0000x reference)
//
#include <hip/hip_runtime.h>

// Grouped GEMM: a[M,512] fp32 (rows contiguous by group) x b[g][512,512] fp32
// -> out[M,512] fp32. group_list = cumulative end rows.
// 128x128 tile / block, BK=64, fp32->bf16 cvt during staging,
// mfma_f32_16x16x32_bf16, fp32 accum.
// R2: software pipeline — register prefetch of next K-tile issued AFTER the
// barrier (barrier emits vmcnt(0) drain), double-buffered LDS -> single
// barrier per K-iter.
// R3: XCD-affine group swizzle. G==8==NXCD and each group is exactly 64
// blocks == one XCD's residency (32 CU x 2 blocks/CU). Map group g -> XCD g
// (blocks dispatch round-robin, xcd = blockIdx.x % 8): the group's 1 MB B
// matrix becomes L2-resident (reused 16x), and the 4 tn-blocks sharing an
// A-tile are temporally adjacent on the SAME XCD (A L2 reuse 4x). Cuts
// cross-die read traffic ~268 MB -> ~unique bytes.

#define KDIM 512
#define NDIM 512
#define BM 128
#define BN 128
#define BK 64
#define LDSTRIDE 72   // 64 + 8 bf16 pad (144 B rows -> even bank spread)

typedef __bf16 bf16x8 __attribute__((ext_vector_type(8)));
typedef __bf16 bf16x4 __attribute__((ext_vector_type(4)));
typedef float  f32x4  __attribute__((ext_vector_type(4)));

__global__ __launch_bounds__(256, 2)
void grouped_gemm_kernel(const float* __restrict__ A,
                         const float* __restrict__ B,
                         const int*   __restrict__ glist,
                         float*       __restrict__ C,
                         int M, int G)
{
    __shared__ __bf16 As[2][BM * LDSTRIDE];   // 2 x 18 KiB
    __shared__ __bf16 Bs[2][BN * LDSTRIDE];   // 2 x 18 KiB  (72 KiB total)

    const int nTilesN = NDIM / BN;             // 4
    const int nTilesM = M / BM;                // 128

    // ---- R3: XCD-affine swizzle ----
    // Hardware round-robins blocks across 8 XCDs: xcd = blockIdx.x % 8.
    // When the grid factors as 8 groups x 16 tm x 4 tn (the benchmark shape),
    // give XCD x all 64 tiles of group x; within the XCD, consecutive slots
    // share the same A-tile (tn fastest). Generic fallback otherwise.
    int tm, tn;
    const int tilesPerGroup = (nTilesM / 8) * nTilesN;   // 64 when M=16384
    if (G == 8 && (nTilesM % 8) == 0 && gridDim.x == (unsigned)(nTilesM * nTilesN)) {
        const int x = blockIdx.x & 7;          // physical XCD
        const int s = blockIdx.x >> 3;         // slot within XCD, 0..tilesPerGroup-1
        tm = x * (nTilesM / 8) + s / nTilesN;
        tn = s % nTilesN;
        (void)tilesPerGroup;
    } else {
        tm = blockIdx.x / nTilesN;
        tn = blockIdx.x % nTilesN;
    }

    const int row0 = tm * BM;
    const int col0 = tn * BN;

    // searchsorted(group_list, row0, side='right'); tiles never straddle groups
    int gid = 0;
    for (int g = 0; g < G; ++g) gid += (glist[g] <= row0) ? 1 : 0;
    const float* Bg = B + (size_t)gid * KDIM * NDIM;

    const int t    = threadIdx.x;
    const int lane = t & 63;
    const int wave = t >> 6;
    const int wm   = wave >> 1;
    const int wn   = wave & 1;
    const int lm   = lane & 15;
    const int quad = lane >> 4;

    // A staging: 8 floats along K x 4 rows (stride 32)
    const int a_seg = t & 7;
    const int a_row = t >> 3;
    // B staging: 8 n-cols x 4 k-rows
    const int b_n0  = (t & 15) * 8;
    const int b_k0  = (t >> 4) * 4;

    const float* aptr = A + (size_t)(row0 + a_row) * KDIM + a_seg * 8;
    const float* bptr = Bg + (size_t)b_k0 * NDIM + col0 + b_n0;

    f32x4 ra[4][2], rb[4][2];

    // ---- prologue: load K-tile 0 into registers ----
#pragma unroll
    for (int s = 0; s < 4; ++s) {
        const float* p = aptr + (size_t)(s * 32) * KDIM;
        ra[s][0] = *(const f32x4*)p;
        ra[s][1] = *(const f32x4*)(p + 4);
    }
#pragma unroll
    for (int dk = 0; dk < 4; ++dk) {
        const float* p = bptr + (size_t)dk * NDIM;
        rb[dk][0] = *(const f32x4*)p;
        rb[dk][1] = *(const f32x4*)(p + 4);
    }

    f32x4 acc[4][4];
#pragma unroll
    for (int i = 0; i < 4; ++i)
#pragma unroll
        for (int j = 0; j < 4; ++j)
            acc[i][j] = (f32x4){0.f, 0.f, 0.f, 0.f};

    const int NITER = KDIM / BK;               // 8
    for (int it = 0; it < NITER; ++it) {
        __bf16* as = As[it & 1];
        __bf16* bs = Bs[it & 1];

        // ---- cvt + stage A from registers (waits vmcnt here) ----
#pragma unroll
        for (int s = 0; s < 4; ++s) {
            const int r = a_row + s * 32;
            bf16x8 w;
            w[0] = (__bf16)ra[s][0][0]; w[1] = (__bf16)ra[s][0][1];
            w[2] = (__bf16)ra[s][0][2]; w[3] = (__bf16)ra[s][0][3];
            w[4] = (__bf16)ra[s][1][0]; w[5] = (__bf16)ra[s][1][1];
            w[6] = (__bf16)ra[s][1][2]; w[7] = (__bf16)ra[s][1][3];
            *(bf16x8*)&as[r * LDSTRIDE + a_seg * 8] = w;
        }
        // ---- cvt + stage B transposed [n][k], 16B-granule XOR swizzle ----
#pragma unroll
        for (int dn = 0; dn < 8; ++dn) {
            const int n = b_n0 + dn;
            bf16x4 w;
#pragma unroll
            for (int dk = 0; dk < 4; ++dk)
                w[dk] = (__bf16)rb[dk][dn >> 2][dn & 3];
            const int g16  = b_k0 >> 3;
            const int half = (b_k0 >> 2) & 1;
            const int phys = g16 ^ ((n >> 3) & 7);
            *(bf16x4*)&bs[n * LDSTRIDE + phys * 8 + half * 4] = w;
        }

        __syncthreads();   // single barrier: drains ds_writes + prior reads

        // ---- prefetch next K-tile AFTER the barrier (not drained by it);
        //      vmcnt wait lands at next iter's cvt, hidden by frags+MFMA ----
        if (it < NITER - 1) {
            const int kb = (it + 1) * BK;
#pragma unroll
            for (int s = 0; s < 4; ++s) {
                const float* p = aptr + (size_t)(s * 32) * KDIM + kb;
                ra[s][0] = *(const f32x4*)p;
                ra[s][1] = *(const f32x4*)(p + 4);
            }
#pragma unroll
            for (int dk = 0; dk < 4; ++dk) {
                const float* p = bptr + (size_t)(kb + dk) * NDIM;
                rb[dk][0] = *(const f32x4*)p;
                rb[dk][1] = *(const f32x4*)(p + 4);
            }
        }

        // ---- fragments + 32 MFMAs ----
#pragma unroll
        for (int ks = 0; ks < 2; ++ks) {
            const int g16 = ks * 4 + quad;
            bf16x8 af[4], bfr[4];
#pragma unroll
            for (int i = 0; i < 4; ++i) {
                const int m = wm * 64 + i * 16 + lm;
                af[i] = *(const bf16x8*)&as[m * LDSTRIDE + g16 * 8];
            }
#pragma unroll
            for (int j = 0; j < 4; ++j) {
                const int n = wn * 64 + j * 16 + lm;
                const int phys = g16 ^ ((n >> 3) & 7);
                bfr[j] = *(const bf16x8*)&bs[n * LDSTRIDE + phys * 8];
            }
#pragma unroll
            for (int i = 0; i < 4; ++i)
#pragma unroll
                for (int j = 0; j < 4; ++j)
                    acc[i][j] = __builtin_amdgcn_mfma_f32_16x16x32_bf16(
                        af[i], bfr[j], acc[i][j], 0, 0, 0);
        }
        // no trailing barrier: next iter writes the OTHER buffer; reuse of
        // this one is ordered by the next iter's barrier.
    }

    // ---- epilogue: C/D layout col=lane&15, row=quad*4+reg ----
#pragma unroll
    for (int i = 0; i < 4; ++i) {
        const int gr0 = row0 + wm * 64 + i * 16 + quad * 4;
#pragma unroll
        for (int j = 0; j < 4; ++j) {
            const int gc = col0 + wn * 64 + j * 16 + lm;
#pragma unroll
            for (int r = 0; r < 4; ++r)
                C[(size_t)(gr0 + r) * NDIM + gc] = acc[i][j][r];
        }
    }
}

extern "C" void kernel_launch(void* const* d_in, const int* in_sizes, int n_in,
                              void* d_out, int out_size, void* d_ws, size_t ws_size,
                              hipStream_t stream) {
    const float* a  = (const float*)d_in[0];
    const float* b  = (const float*)d_in[1];
    const int*   gl = (const int*)d_in[2];
    float* out = (float*)d_out;

    const int M = in_sizes[0] / KDIM;          // 16384
    const int G = in_sizes[2];                 // 8

    dim3 grid((M / BM) * (NDIM / BN));         // 512 blocks = 2/CU
    grouped_gemm_kernel<<<grid, 256, 0, stream>>>(a, b, gl, out, M, G);
}

// Round 2
// 108.339 us; speedup vs baseline: 1.0018x; 1.0018x over previous
//
#include <hip/hip_runtime.h>

// Grouped GEMM: a[M,512] fp32 (rows contiguous by group) x b[g][512,512] fp32
// -> out[M,512] fp32. group_list = cumulative end rows.
// 128x128 tile / block, BK=64, fp32->bf16 cvt during staging,
// mfma_f32_16x16x32_bf16, fp32 accum.
// R2: software pipeline — register prefetch of next K-tile issued AFTER the
// barrier (barrier emits vmcnt(0) drain), double-buffered LDS -> single
// barrier per K-iter.
// R3 (XCD group swizzle): REVERTED — whole read footprint (42 MB) is
// L3-resident, so per-XCD L2 locality gains are absorbed by Infinity Cache;
// measured neutral-to-negative (104.4 -> 108.5 us).
// R4: occupancy. 72 KB LDS caps us at 2 blocks/CU; with 256-thread blocks
// that is 2 waves/SIMD — too little TLP to hide the ~200-900 cy load latency
// behind only ~155 cy of MFMA per K-iter (per-iter vmcnt stall at the cvt).
// Same 128x128 tile with 512-thread blocks: still 2 blocks/CU but
// 16 waves/CU = 4 waves/SIMD from two barrier-independent blocks. Per-wave
// state halves (wave owns 64x32, acc[4][2]=32 VGPR; 8 prefetch loads/thread)
// so VGPR fits the 128-reg/4-wave budget.

#define KDIM 512
#define NDIM 512
#define BM 128
#define BN 128
#define BK 64
#define LDSTRIDE 72   // 64 + 8 bf16 pad (144 B rows -> even bank spread)

typedef __bf16 bf16x8 __attribute__((ext_vector_type(8)));
typedef __bf16 bf16x2 __attribute__((ext_vector_type(2)));
typedef float  f32x4  __attribute__((ext_vector_type(4)));

__global__ __launch_bounds__(512, 4)
void grouped_gemm_kernel(const float* __restrict__ A,
                         const float* __restrict__ B,
                         const int*   __restrict__ glist,
                         float*       __restrict__ C,
                         int M, int G)
{
    __shared__ __bf16 As[2][BM * LDSTRIDE];   // 2 x 18 KiB
    __shared__ __bf16 Bs[2][BN * LDSTRIDE];   // 2 x 18 KiB  (72 KiB total)

    const int nTilesN = NDIM / BN;             // 4
    const int tm = blockIdx.x / nTilesN;
    const int tn = blockIdx.x % nTilesN;
    const int row0 = tm * BM;
    const int col0 = tn * BN;

    // searchsorted(group_list, row0, side='right'); tiles never straddle groups
    int gid = 0;
    for (int g = 0; g < G; ++g) gid += (glist[g] <= row0) ? 1 : 0;
    const float* Bg = B + (size_t)gid * KDIM * NDIM;

    const int t    = threadIdx.x;
    const int lane = t & 63;
    const int wave = t >> 6;                   // 0..7
    const int wm   = wave >> 2;                // 0..1  (64-row half)
    const int wn   = wave & 3;                 // 0..3  (32-col strip)
    const int lm   = lane & 15;
    const int quad = lane >> 4;

    // A staging: 8 floats along K x 64 rows per pass, 2 passes (stride 64)
    const int a_seg = t & 7;
    const int a_row = t >> 3;                  // 0..63
    // B staging: 8 n-cols x 2 k-rows per thread
    const int b_n0  = (t & 15) * 8;
    const int b_k0  = (t >> 4) * 2;            // 0..62 step 2

    const float* aptr = A + (size_t)(row0 + a_row) * KDIM + a_seg * 8;
    const float* bptr = Bg + (size_t)b_k0 * NDIM + col0 + b_n0;

    f32x4 ra[2][2], rb[2][2];

    // ---- prologue: load K-tile 0 into registers ----
#pragma unroll
    for (int s = 0; s < 2; ++s) {
        const float* p = aptr + (size_t)(s * 64) * KDIM;
        ra[s][0] = *(const f32x4*)p;
        ra[s][1] = *(const f32x4*)(p + 4);
    }
#pragma unroll
    for (int dk = 0; dk < 2; ++dk) {
        const float* p = bptr + (size_t)dk * NDIM;
        rb[dk][0] = *(const f32x4*)p;
        rb[dk][1] = *(const f32x4*)(p + 4);
    }

    f32x4 acc[4][2];
#pragma unroll
    for (int i = 0; i < 4; ++i)
#pragma unroll
        for (int j = 0; j < 2; ++j)
            acc[i][j] = (f32x4){0.f, 0.f, 0.f, 0.f};

    const int NITER = KDIM / BK;               // 8
    for (int it = 0; it < NITER; ++it) {
        __bf16* as = As[it & 1];
        __bf16* bs = Bs[it & 1];

        // ---- cvt + stage A from registers (waits vmcnt here) ----
#pragma unroll
        for (int s = 0; s < 2; ++s) {
            const int r = a_row + s * 64;
            bf16x8 w;
            w[0] = (__bf16)ra[s][0][0]; w[1] = (__bf16)ra[s][0][1];
            w[2] = (__bf16)ra[s][0][2]; w[3] = (__bf16)ra[s][0][3];
            w[4] = (__bf16)ra[s][1][0]; w[5] = (__bf16)ra[s][1][1];
            w[6] = (__bf16)ra[s][1][2]; w[7] = (__bf16)ra[s][1][3];
            *(bf16x8*)&as[r * LDSTRIDE + a_seg * 8] = w;
        }
        // ---- cvt + stage B transposed [n][k], 16B-granule XOR swizzle ----
        // element (n,k) lives at bs[n*LDSTRIDE + ((k>>3)^((n>>3)&7))*8 + (k&7)]
#pragma unroll
        for (int dn = 0; dn < 8; ++dn) {
            const int n = b_n0 + dn;
            bf16x2 w;
            w[0] = (__bf16)rb[0][dn >> 2][dn & 3];
            w[1] = (__bf16)rb[1][dn >> 2][dn & 3];
            const int g16  = b_k0 >> 3;
            const int phys = g16 ^ ((n >> 3) & 7);
            *(bf16x2*)&bs[n * LDSTRIDE + phys * 8 + (b_k0 & 7)] = w;
        }

        __syncthreads();   // single barrier: drains ds_writes + prior reads

        // ---- prefetch next K-tile AFTER the barrier (not drained by it);
        //      vmcnt wait lands at next iter's cvt, hidden by frags+MFMA
        //      of this iter + the 3 other waves/SIMD ----
        if (it < NITER - 1) {
            const int kb = (it + 1) * BK;
#pragma unroll
            for (int s = 0; s < 2; ++s) {
                const float* p = aptr + (size_t)(s * 64) * KDIM + kb;
                ra[s][0] = *(const f32x4*)p;
                ra[s][1] = *(const f32x4*)(p + 4);
            }
#pragma unroll
            for (int dk = 0; dk < 2; ++dk) {
                const float* p = bptr + (size_t)(kb + dk) * NDIM;
                rb[dk][0] = *(const f32x4*)p;
                rb[dk][1] = *(const f32x4*)(p + 4);
            }
        }

        // ---- fragments + 16 MFMAs per wave ----
#pragma unroll
        for (int ks = 0; ks < 2; ++ks) {
            const int g16 = ks * 4 + quad;
            bf16x8 af[4], bfr[2];
#pragma unroll
            for (int i = 0; i < 4; ++i) {
                const int m = wm * 64 + i * 16 + lm;
                af[i] = *(const bf16x8*)&as[m * LDSTRIDE + g16 * 8];
            }
#pragma unroll
            for (int j = 0; j < 2; ++j) {
                const int n = wn * 32 + j * 16 + lm;
                const int phys = g16 ^ ((n >> 3) & 7);
                bfr[j] = *(const bf16x8*)&bs[n * LDSTRIDE + phys * 8];
            }
#pragma unroll
            for (int i = 0; i < 4; ++i)
#pragma unroll
                for (int j = 0; j < 2; ++j)
                    acc[i][j] = __builtin_amdgcn_mfma_f32_16x16x32_bf16(
                        af[i], bfr[j], acc[i][j], 0, 0, 0);
        }
        // no trailing barrier: next iter writes the OTHER buffer; reuse of
        // this one is ordered by the next iter's barrier.
    }

    // ---- epilogue: C/D layout col=lane&15, row=quad*4+reg ----
#pragma unroll
    for (int i = 0; i < 4; ++i) {
        const int gr0 = row0 + wm * 64 + i * 16 + quad * 4;
#pragma unroll
        for (int j = 0; j < 2; ++j) {
            const int gc = col0 + wn * 32 + j * 16 + lm;
#pragma unroll
            for (int r = 0; r < 4; ++r)
                C[(size_t)(gr0 + r) * NDIM + gc] = acc[i][j][r];
        }
    }
}

extern "C" void kernel_launch(void* const* d_in, const int* in_sizes, int n_in,
                              void* d_out, int out_size, void* d_ws, size_t ws_size,
                              hipStream_t stream) {
    const float* a  = (const float*)d_in[0];
    const float* b  = (const float*)d_in[1];
    const int*   gl = (const int*)d_in[2];
    float* out = (float*)d_out;

    const int M = in_sizes[0] / KDIM;          // 16384
    const int G = in_sizes[2];                 // 8

    dim3 grid((M / BM) * (NDIM / BN));         // 512 blocks = 2/CU
    grouped_gemm_kernel<<<grid, 512, 0, stream>>>(a, b, gl, out, M, G);
}

// Round 6
// 105.027 us; speedup vs baseline: 1.0334x; 1.0315x over previous
//
#include <hip/hip_runtime.h>

// Grouped GEMM: a[M,512] fp32 (rows contiguous by group) x b[g][512,512] fp32
// -> out[M,512] fp32. group_list = cumulative end rows.
// 128x128 tile / block, 256 threads (4 waves, each owns 64x64 = acc[4][4] --
// best LDS economy: 8 frag reads per 16 MFMAs), BK=64, fp32->bf16 cvt during
// staging, mfma_f32_16x16x32_bf16, fp32 accum.
// R2: register prefetch issued AFTER the barrier (barrier emits vmcnt(0)
// drain), double-buffered LDS -> single barrier per K-iter.
// R3 (XCD swizzle): REVERTED — 42 MB read set is L3-resident; measured -4us.
// R4 (512-thr): REVERTED — occupancy doubling was canceled by +50% LDS
// fragment traffic (confounded; measured neutral at 108.3).
// R5: 2-deep A prefetch. A is the cold stream (33.5 MB, ~900 cy misses);
// 1-deep gave only a ~1-phase (~350 cy) issue->consume window = per-iter
// vmcnt stall at the A-cvt. Manual unroll-by-2 with named ping-pong regs
// raA/raB (static indexing; runtime-indexed ext_vector arrays go to scratch)
// gives A a 2-phase (~700-800 cy) window. B stays 1-deep (L2-hot, ~200 cy).
// Issue B-before-A post-barrier: the A-consume wait then tolerates 16
// outstanding loads (counted-vmcnt effect). VGPR ~210 of 256 budget; still
// 2 blocks/CU.
// (R5 resubmitted — three consecutive GPU-acquisition failures; kernel has
// never been measured.)

#define KDIM 512
#define NDIM 512
#define BM 128
#define BN 128
#define BK 64
#define LDSTRIDE 72   // 64 + 8 bf16 pad (144 B rows -> even bank spread)

typedef __bf16 bf16x8 __attribute__((ext_vector_type(8)));
typedef __bf16 bf16x4 __attribute__((ext_vector_type(4)));
typedef float  f32x4  __attribute__((ext_vector_type(4)));

__global__ __launch_bounds__(256, 2)
void grouped_gemm_kernel(const float* __restrict__ A,
                         const float* __restrict__ B,
                         const int*   __restrict__ glist,
                         float*       __restrict__ C,
                         int M, int G)
{
    __shared__ __bf16 As[2][BM * LDSTRIDE];   // 2 x 18 KiB
    __shared__ __bf16 Bs[2][BN * LDSTRIDE];   // 2 x 18 KiB  (72 KiB total)

    const int nTilesN = NDIM / BN;             // 4
    const int tm = blockIdx.x / nTilesN;
    const int tn = blockIdx.x % nTilesN;
    const int row0 = tm * BM;
    const int col0 = tn * BN;

    // searchsorted(group_list, row0, side='right'); tiles never straddle groups
    int gid = 0;
    for (int g = 0; g < G; ++g) gid += (glist[g] <= row0) ? 1 : 0;
    const float* Bg = B + (size_t)gid * KDIM * NDIM;

    const int t    = threadIdx.x;
    const int lane = t & 63;
    const int wave = t >> 6;
    const int wm   = wave >> 1;
    const int wn   = wave & 1;
    const int lm   = lane & 15;
    const int quad = lane >> 4;

    // A staging: 8 floats along K x 4 rows (stride 32)
    const int a_seg = t & 7;
    const int a_row = t >> 3;
    // B staging: 8 n-cols x 4 k-rows
    const int b_n0  = (t & 15) * 8;
    const int b_k0  = (t >> 4) * 4;

    const float* aptr = A + (size_t)(row0 + a_row) * KDIM + a_seg * 8;
    const float* bptr = Bg + (size_t)b_k0 * NDIM + col0 + b_n0;

    f32x4 raA[4][2], raB[4][2], rb[4][2];

#define LOAD_A(dst, kb)                                                     \
    {                                                                       \
        _Pragma("unroll")                                                   \
        for (int s = 0; s < 4; ++s) {                                       \
            const float* p = aptr + (size_t)(s * 32) * KDIM + (kb);         \
            dst[s][0] = *(const f32x4*)p;                                   \
            dst[s][1] = *(const f32x4*)(p + 4);                             \
        }                                                                   \
    }

#define LOAD_B(kb)                                                          \
    {                                                                       \
        _Pragma("unroll")                                                   \
        for (int dk = 0; dk < 4; ++dk) {                                    \
            const float* p = bptr + (size_t)((kb) + dk) * NDIM;             \
            rb[dk][0] = *(const f32x4*)p;                                   \
            rb[dk][1] = *(const f32x4*)(p + 4);                             \
        }                                                                   \
    }

    // cvt + stage A from regs; cvt + stage B transposed [n][k] with
    // 16B-granule XOR swizzle: (n,k) -> bs[n*LDSTRIDE + ((k>>3)^((n>>3)&7))*8 + (k&7)]
#define STAGE(buf, ra)                                                      \
    {                                                                       \
        __bf16* as_ = As[buf];                                              \
        __bf16* bs_ = Bs[buf];                                              \
        _Pragma("unroll")                                                   \
        for (int s = 0; s < 4; ++s) {                                       \
            const int r = a_row + s * 32;                                   \
            bf16x8 w;                                                       \
            w[0] = (__bf16)ra[s][0][0]; w[1] = (__bf16)ra[s][0][1];         \
            w[2] = (__bf16)ra[s][0][2]; w[3] = (__bf16)ra[s][0][3];         \
            w[4] = (__bf16)ra[s][1][0]; w[5] = (__bf16)ra[s][1][1];         \
            w[6] = (__bf16)ra[s][1][2]; w[7] = (__bf16)ra[s][1][3];         \
            *(bf16x8*)&as_[r * LDSTRIDE + a_seg * 8] = w;                   \
        }                                                                   \
        _Pragma("unroll")                                                   \
        for (int dn = 0; dn < 8; ++dn) {                                    \
            const int n = b_n0 + dn;                                        \
            bf16x4 w;                                                       \
            _Pragma("unroll")                                               \
            for (int dk = 0; dk < 4; ++dk)                                  \
                w[dk] = (__bf16)rb[dk][dn >> 2][dn & 3];                    \
            const int g16  = b_k0 >> 3;                                     \
            const int half = (b_k0 >> 2) & 1;                               \
            const int phys = g16 ^ ((n >> 3) & 7);                          \
            *(bf16x4*)&bs_[n * LDSTRIDE + phys * 8 + half * 4] = w;         \
        }                                                                   \
    }

#define MFMA_STEP(buf)                                                      \
    {                                                                       \
        const __bf16* as_ = As[buf];                                        \
        const __bf16* bs_ = Bs[buf];                                        \
        _Pragma("unroll")                                                   \
        for (int ks = 0; ks < 2; ++ks) {                                    \
            const int g16 = ks * 4 + quad;                                  \
            bf16x8 af[4], bfr[4];                                           \
            _Pragma("unroll")                                               \
            for (int i = 0; i < 4; ++i) {                                   \
                const int m = wm * 64 + i * 16 + lm;                        \
                af[i] = *(const bf16x8*)&as_[m * LDSTRIDE + g16 * 8];       \
            }                                                               \
            _Pragma("unroll")                                               \
            for (int j = 0; j < 4; ++j) {                                   \
                const int n = wn * 64 + j * 16 + lm;                        \
                const int phys = g16 ^ ((n >> 3) & 7);                      \
                bfr[j] = *(const bf16x8*)&bs_[n * LDSTRIDE + phys * 8];     \
            }                                                               \
            _Pragma("unroll")                                               \
            for (int i = 0; i < 4; ++i)                                     \
                _Pragma("unroll")                                           \
                for (int j = 0; j < 4; ++j)                                 \
                    acc[i][j] = __builtin_amdgcn_mfma_f32_16x16x32_bf16(    \
                        af[i], bfr[j], acc[i][j], 0, 0, 0);                 \
        }                                                                   \
    }

    // ---- prologue: A tile0 -> raA, B tile0 -> rb, A tile1 -> raB ----
    LOAD_A(raA, 0);
    LOAD_B(0);
    LOAD_A(raB, BK);

    f32x4 acc[4][4];
#pragma unroll
    for (int i = 0; i < 4; ++i)
#pragma unroll
        for (int j = 0; j < 4; ++j)
            acc[i][j] = (f32x4){0.f, 0.f, 0.f, 0.f};

    // NITER = 8 sub-iters, unrolled x2: even uses raA/buf0, odd raB/buf1.
    for (int ii = 0; ii < 4; ++ii) {
        const int k0 = ii * 2 * BK;

        // ---- even sub-iter: K-tile 2ii ----
        STAGE(0, raA);                 // vmcnt wait on raA (oldest) + rb
        __syncthreads();
        LOAD_B(k0 + BK);               // B tile 2ii+1 (1-deep, L2-hot)
        if (ii < 3) LOAD_A(raA, k0 + 2 * BK);   // A tile 2ii+2 (2-deep)
        MFMA_STEP(0);

        // ---- odd sub-iter: K-tile 2ii+1 ----
        STAGE(1, raB);
        __syncthreads();
        if (ii < 3) {
            LOAD_B(k0 + 2 * BK);               // B tile 2ii+2
            LOAD_A(raB, k0 + 3 * BK);          // A tile 2ii+3 (2-deep)
        }
        MFMA_STEP(1);
        // no trailing barrier: next sub-iter writes the OTHER buffer; reuse
        // of this one is ordered by that sub-iter's barrier.
    }

    // ---- epilogue: C/D layout col=lane&15, row=quad*4+reg ----
#pragma unroll
    for (int i = 0; i < 4; ++i) {
        const int gr0 = row0 + wm * 64 + i * 16 + quad * 4;
#pragma unroll
        for (int j = 0; j < 4; ++j) {
            const int gc = col0 + wn * 64 + j * 16 + lm;
#pragma unroll
            for (int r = 0; r < 4; ++r)
                C[(size_t)(gr0 + r) * NDIM + gc] = acc[i][j][r];
        }
    }

#undef LOAD_A
#undef LOAD_B
#undef STAGE
#undef MFMA_STEP
}

extern "C" void kernel_launch(void* const* d_in, const int* in_sizes, int n_in,
                              void* d_out, int out_size, void* d_ws, size_t ws_size,
                              hipStream_t stream) {
    const float* a  = (const float*)d_in[0];
    const float* b  = (const float*)d_in[1];
    const int*   gl = (const int*)d_in[2];
    float* out = (float*)d_out;

    const int M = in_sizes[0] / KDIM;          // 16384
    const int G = in_sizes[2];                 // 8

    dim3 grid((M / BM) * (NDIM / BN));         // 512 blocks = 2/CU
    grouped_gemm_kernel<<<grid, 256, 0, stream>>>(a, b, gl, out, M, G);
}